// Round 1
// baseline (1730.178 us; speedup 1.0000x reference)
//
#include <hip/hip_runtime.h>
#include <math.h>

#define NROWS 65536
#define LLEN  1024
#define NCLS  4

struct Acc {
    double d2_sum;     // sum of second-difference^2 over all B*L elements
    double nll_sum;    // sum of masked NLL
    double pen_sum;    // sum of physics penalties
    unsigned int n_valid;
    float gmax;        // global max of waveform
};

__device__ __forceinline__ void atomicMaxFloat(float* addr, float val) {
    int* a = (int*)addr;
    int old = __float_as_int(*addr);
    while (__int_as_float(old) < val) {
        int assumed = old;
        old = atomicCAS(a, assumed, __float_as_int(val));
        if (old == assumed) break;
    }
}

__global__ void init_kernel(Acc* acc) {
    acc->d2_sum = 0.0;
    acc->nll_sum = 0.0;
    acc->pen_sum = 0.0;
    acc->n_valid = 0u;
    acc->gmax = -INFINITY;
}

// One wave (64 lanes) per row; 4 waves / block. Stages the row in LDS so the
// waveform is read from HBM exactly once (268 MB total -> memory-bound floor).
__global__ __launch_bounds__(256) void row_kernel(const float* __restrict__ wf,
                                                  const float* __restrict__ depth,
                                                  float* __restrict__ eraw,
                                                  Acc* __restrict__ acc) {
    __shared__ float lds[4][LLEN];
    const int wave = threadIdx.x >> 6;
    const int lane = threadIdx.x & 63;
    const int row  = blockIdx.x * 4 + wave;

    // coalesced float4 stage: 256 float4 per row, 4 per lane
    const float4* src = (const float4*)(wf + (size_t)row * LLEN);
    float4* dst = (float4*)lds[wave];
#pragma unroll
    for (int j = 0; j < 4; ++j) dst[lane + 64 * j] = src[lane + 64 * j];
    __syncthreads();

    const float tpos = depth[row] * 10.0f;   // 2*d/4000*20000
    const float* w = lds[wave];

    float d2s = 0.0f, wsum = 0.0f, wesum = 0.0f, mx = -INFINITY;
#pragma unroll
    for (int k = 0; k < 16; ++k) {
        const int idx = k * 64 + lane;       // conflict-free LDS pattern
        const float c = w[idx];
        float d2;
        if (idx == 0)            d2 = w[1] - c;                     // w1 - 2w0 + w0
        else if (idx == LLEN - 1) d2 = w[LLEN - 2] - c;             // w[-2] - w[-1]
        else                     d2 = w[idx + 1] - 2.0f * c + w[idx - 1];
        d2s += d2 * d2;
        mx = fmaxf(mx, c);
        const float dt = ((float)idx - tpos) * 0.2f;                // /sigma, sigma=5
        const float g = __expf(-0.5f * dt * dt);
        wsum  += g;
        wesum += c * c * g;
    }

#pragma unroll
    for (int off = 32; off > 0; off >>= 1) {
        d2s   += __shfl_down(d2s,   off, 64);
        wsum  += __shfl_down(wsum,  off, 64);
        wesum += __shfl_down(wesum, off, 64);
        mx = fmaxf(mx, __shfl_down(mx, off, 64));
    }

    if (lane == 0) {
        eraw[row] = wesum / wsum;            // normalized-window energy (pre global-max div)
        atomicAdd(&acc->d2_sum, (double)d2s);
        atomicMaxFloat(&acc->gmax, mx);
    }
}

// Per-row: masked CE, argmax class, physics penalty (needs gmax from kernel 1).
__global__ __launch_bounds__(256) void cls_kernel(const float* __restrict__ logits,
                                                  const int* __restrict__ labels,
                                                  const float* __restrict__ eraw,
                                                  Acc* __restrict__ acc) {
    const int r = blockIdx.x * 256 + threadIdx.x;
    const float4 lg = ((const float4*)logits)[r];

    const float m = fmaxf(fmaxf(lg.x, lg.y), fmaxf(lg.z, lg.w));
    const float lse = m + logf(__expf(lg.x - m) + __expf(lg.y - m) +
                               __expf(lg.z - m) + __expf(lg.w - m));

    const int lab = labels[r];
    const bool valid = (lab != -1);
    const int sl = valid ? lab : 0;
    const float lv = (sl == 0) ? lg.x : (sl == 1) ? lg.y : (sl == 2) ? lg.z : lg.w;
    float nll = valid ? (lse - lv) : 0.0f;

    // first-occurrence argmax (strict >)
    int pc = 0; float bv = lg.x;
    if (lg.y > bv) { bv = lg.y; pc = 1; }
    if (lg.z > bv) { bv = lg.z; pc = 2; }
    if (lg.w > bv) { bv = lg.w; pc = 3; }

    const float E = eraw[r] / (20.0f * acc->gmax);
    const bool isdef = (pc == 2) || (pc == 3);
    float pen;
    if (isdef) pen = (E < 0.1f) ? (0.1f - E) * (0.1f - E) : 0.0f;
    else       pen = (E > 0.5f) ? (E - 0.5f) * (E - 0.5f) : 0.0f;

    const unsigned long long bal = __ballot(valid);
#pragma unroll
    for (int off = 32; off > 0; off >>= 1) {
        nll += __shfl_down(nll, off, 64);
        pen += __shfl_down(pen, off, 64);
    }
    if ((threadIdx.x & 63) == 0) {
        atomicAdd(&acc->nll_sum, (double)nll);
        atomicAdd(&acc->pen_sum, (double)pen);
        atomicAdd(&acc->n_valid, (unsigned int)__popcll(bal));
    }
}

__global__ void final_kernel(const Acc* __restrict__ acc, float* __restrict__ out) {
    const double cls  = (acc->n_valid > 0) ? acc->nll_sum / (double)acc->n_valid : 0.0;
    // residual = d2*(1/DT^2 - C^2/DX^2) = d2*(10000 - 100) = d2*9900
    const double wave = acc->d2_sum * (9900.0 * 9900.0) / ((double)NROWS * (double)LLEN);
    const double phys = acc->pen_sum / (double)NROWS;
    const double total = cls + 0.1 * wave + 0.1 * phys;
    out[0] = (float)total;
    out[1] = (float)cls;
    out[2] = (float)wave;
    out[3] = (float)phys;
}

extern "C" void kernel_launch(void* const* d_in, const int* in_sizes, int n_in,
                              void* d_out, int out_size, void* d_ws, size_t ws_size,
                              hipStream_t stream) {
    const float* wf     = (const float*)d_in[0];  // (B, L) f32
    const float* logits = (const float*)d_in[1];  // (B, 4) f32
    const float* depth  = (const float*)d_in[2];  // (B, 1) f32
    const int*   labels = (const int*)d_in[3];    // (B,) int32
    float* out = (float*)d_out;

    Acc*   acc  = (Acc*)d_ws;
    float* eraw = (float*)((char*)d_ws + 256);    // B floats of scratch

    init_kernel<<<1, 1, 0, stream>>>(acc);
    row_kernel<<<NROWS / 4, 256, 0, stream>>>(wf, depth, eraw, acc);
    cls_kernel<<<NROWS / 256, 256, 0, stream>>>(logits, labels, eraw, acc);
    final_kernel<<<1, 1, 0, stream>>>(acc, out);
}

// Round 2
// 377.143 us; speedup vs baseline: 4.5876x; 4.5876x over previous
//
#include <hip/hip_runtime.h>
#include <math.h>

#define NROWS 65536
#define LLEN  1024
#define RBLOCKS (NROWS / 4)     // 16384 row-kernel blocks (4 rows each)
#define CBLOCKS (NROWS / 256)   // 256 cls-kernel blocks

struct Acc {
    double d2_sum;
    float  gmax;
};

// ---------------- kernel 1: waveform pass (memory-bound) ----------------
// One wave per row, 4 rows per block. Row staged in LDS -> waveform read
// from HBM exactly once. NO global atomics: per-block partials to d_ws.
__global__ __launch_bounds__(256) void row_kernel(const float* __restrict__ wf,
                                                  const float* __restrict__ depth,
                                                  float* __restrict__ eraw,
                                                  float* __restrict__ d2_part,
                                                  float* __restrict__ mx_part) {
    __shared__ float lds[4][LLEN];
    __shared__ float s_d2[4], s_mx[4];
    const int wave = threadIdx.x >> 6;
    const int lane = threadIdx.x & 63;
    const int row  = blockIdx.x * 4 + wave;

    const float4* src = (const float4*)(wf + (size_t)row * LLEN);
    float4* dst = (float4*)lds[wave];
#pragma unroll
    for (int j = 0; j < 4; ++j) dst[lane + 64 * j] = src[lane + 64 * j];
    __syncthreads();

    const float tpos = depth[row] * 10.0f;      // (2*d/4000)*20000
    const float* w = lds[wave];

    float d2s = 0.0f, wsum = 0.0f, wesum = 0.0f, mx = -INFINITY;
#pragma unroll
    for (int k = 0; k < 16; ++k) {
        const int idx = k * 64 + lane;
        const float c = w[idx];
        float d2;
        if (idx == 0)             d2 = w[1] - c;
        else if (idx == LLEN - 1) d2 = w[LLEN - 2] - c;
        else                      d2 = w[idx + 1] - 2.0f * c + w[idx - 1];
        d2s += d2 * d2;
        mx = fmaxf(mx, c);
        const float dt = ((float)idx - tpos) * 0.2f;  // sigma = 5
        const float g = __expf(-0.5f * dt * dt);
        wsum  += g;
        wesum += c * c * g;
    }

#pragma unroll
    for (int off = 32; off > 0; off >>= 1) {
        d2s   += __shfl_down(d2s,   off, 64);
        wsum  += __shfl_down(wsum,  off, 64);
        wesum += __shfl_down(wesum, off, 64);
        mx = fmaxf(mx, __shfl_down(mx, off, 64));
    }

    if (lane == 0) {
        eraw[row] = wesum / wsum;
        s_d2[wave] = d2s;
        s_mx[wave] = mx;
    }
    __syncthreads();
    if (threadIdx.x == 0) {
        d2_part[blockIdx.x] = s_d2[0] + s_d2[1] + s_d2[2] + s_d2[3];
        mx_part[blockIdx.x] = fmaxf(fmaxf(s_mx[0], s_mx[1]), fmaxf(s_mx[2], s_mx[3]));
    }
}

// ---------------- kernel 2: fold 16384 partials -> Acc ----------------
__global__ __launch_bounds__(256) void reduce_kernel(const float* __restrict__ d2_part,
                                                     const float* __restrict__ mx_part,
                                                     Acc* __restrict__ acc) {
    __shared__ double s_d2[4];
    __shared__ float  s_mx[4];
    const int wave = threadIdx.x >> 6;
    const int lane = threadIdx.x & 63;

    double d2 = 0.0;
    float mx = -INFINITY;
    for (int i = threadIdx.x; i < RBLOCKS; i += 256) {
        d2 += (double)d2_part[i];
        mx = fmaxf(mx, mx_part[i]);
    }
#pragma unroll
    for (int off = 32; off > 0; off >>= 1) {
        d2 += __shfl_down(d2, off, 64);
        mx = fmaxf(mx, __shfl_down(mx, off, 64));
    }
    if (lane == 0) { s_d2[wave] = d2; s_mx[wave] = mx; }
    __syncthreads();
    if (threadIdx.x == 0) {
        acc->d2_sum = s_d2[0] + s_d2[1] + s_d2[2] + s_d2[3];
        acc->gmax   = fmaxf(fmaxf(s_mx[0], s_mx[1]), fmaxf(s_mx[2], s_mx[3]));
    }
}

// ---------------- kernel 3: CE + argmax + penalty, per-block partials ----------------
__global__ __launch_bounds__(256) void cls_kernel(const float* __restrict__ logits,
                                                  const int* __restrict__ labels,
                                                  const float* __restrict__ eraw,
                                                  const Acc* __restrict__ acc,
                                                  float* __restrict__ nll_part,
                                                  float* __restrict__ pen_part,
                                                  int* __restrict__ nv_part) {
    __shared__ float s_nll[4], s_pen[4];
    __shared__ int   s_nv[4];
    const int wave = threadIdx.x >> 6;
    const int lane = threadIdx.x & 63;
    const int r = blockIdx.x * 256 + threadIdx.x;

    const float4 lg = ((const float4*)logits)[r];
    const float m = fmaxf(fmaxf(lg.x, lg.y), fmaxf(lg.z, lg.w));
    const float lse = m + logf(__expf(lg.x - m) + __expf(lg.y - m) +
                               __expf(lg.z - m) + __expf(lg.w - m));

    const int lab = labels[r];
    const bool valid = (lab != -1);
    const int sl = valid ? lab : 0;
    const float lv = (sl == 0) ? lg.x : (sl == 1) ? lg.y : (sl == 2) ? lg.z : lg.w;
    float nll = valid ? (lse - lv) : 0.0f;

    int pc = 0; float bv = lg.x;
    if (lg.y > bv) { bv = lg.y; pc = 1; }
    if (lg.z > bv) { bv = lg.z; pc = 2; }
    if (lg.w > bv) { bv = lg.w; pc = 3; }

    const float E = eraw[r] / (20.0f * acc->gmax);
    const bool isdef = (pc == 2) || (pc == 3);
    float pen;
    if (isdef) pen = (E < 0.1f) ? (0.1f - E) * (0.1f - E) : 0.0f;
    else       pen = (E > 0.5f) ? (E - 0.5f) * (E - 0.5f) : 0.0f;

    const unsigned long long bal = __ballot(valid);
#pragma unroll
    for (int off = 32; off > 0; off >>= 1) {
        nll += __shfl_down(nll, off, 64);
        pen += __shfl_down(pen, off, 64);
    }
    if (lane == 0) { s_nll[wave] = nll; s_pen[wave] = pen; s_nv[wave] = __popcll(bal); }
    __syncthreads();
    if (threadIdx.x == 0) {
        nll_part[blockIdx.x] = s_nll[0] + s_nll[1] + s_nll[2] + s_nll[3];
        pen_part[blockIdx.x] = s_pen[0] + s_pen[1] + s_pen[2] + s_pen[3];
        nv_part[blockIdx.x]  = s_nv[0] + s_nv[1] + s_nv[2] + s_nv[3];
    }
}

// ---------------- kernel 4: fold 256 cls partials, emit 4 scalars ----------------
__global__ __launch_bounds__(256) void final_kernel(const float* __restrict__ nll_part,
                                                    const float* __restrict__ pen_part,
                                                    const int* __restrict__ nv_part,
                                                    const Acc* __restrict__ acc,
                                                    float* __restrict__ out) {
    __shared__ double s_nll[4], s_pen[4];
    __shared__ int    s_nv[4];
    const int wave = threadIdx.x >> 6;
    const int lane = threadIdx.x & 63;

    double nll = (double)nll_part[threadIdx.x];
    double pen = (double)pen_part[threadIdx.x];
    int nv = nv_part[threadIdx.x];
#pragma unroll
    for (int off = 32; off > 0; off >>= 1) {
        nll += __shfl_down(nll, off, 64);
        pen += __shfl_down(pen, off, 64);
        nv  += __shfl_down(nv,  off, 64);
    }
    if (lane == 0) { s_nll[wave] = nll; s_pen[wave] = pen; s_nv[wave] = nv; }
    __syncthreads();
    if (threadIdx.x == 0) {
        const double nll_s = s_nll[0] + s_nll[1] + s_nll[2] + s_nll[3];
        const double pen_s = s_pen[0] + s_pen[1] + s_pen[2] + s_pen[3];
        const int    nv_s  = s_nv[0] + s_nv[1] + s_nv[2] + s_nv[3];
        const double cls  = (nv_s > 0) ? nll_s / (double)nv_s : 0.0;
        // residual = d2*(1/DT^2 - C^2/DX^2) = d2*9900
        const double wave_l = acc->d2_sum * (9900.0 * 9900.0) / ((double)NROWS * (double)LLEN);
        const double phys = pen_s / (double)NROWS;
        out[0] = (float)(cls + 0.1 * wave_l + 0.1 * phys);
        out[1] = (float)cls;
        out[2] = (float)wave_l;
        out[3] = (float)phys;
    }
}

extern "C" void kernel_launch(void* const* d_in, const int* in_sizes, int n_in,
                              void* d_out, int out_size, void* d_ws, size_t ws_size,
                              hipStream_t stream) {
    const float* wf     = (const float*)d_in[0];
    const float* logits = (const float*)d_in[1];
    const float* depth  = (const float*)d_in[2];
    const int*   labels = (const int*)d_in[3];
    float* out = (float*)d_out;

    char* ws = (char*)d_ws;
    Acc*   acc      = (Acc*)ws;                       ws += 256;
    float* eraw     = (float*)ws;                     ws += NROWS * sizeof(float);
    float* d2_part  = (float*)ws;                     ws += RBLOCKS * sizeof(float);
    float* mx_part  = (float*)ws;                     ws += RBLOCKS * sizeof(float);
    float* nll_part = (float*)ws;                     ws += CBLOCKS * sizeof(float);
    float* pen_part = (float*)ws;                     ws += CBLOCKS * sizeof(float);
    int*   nv_part  = (int*)ws;

    row_kernel<<<RBLOCKS, 256, 0, stream>>>(wf, depth, eraw, d2_part, mx_part);
    reduce_kernel<<<1, 256, 0, stream>>>(d2_part, mx_part, acc);
    cls_kernel<<<CBLOCKS, 256, 0, stream>>>(logits, labels, eraw, acc, nll_part, pen_part, nv_part);
    final_kernel<<<1, 256, 0, stream>>>(nll_part, pen_part, nv_part, acc, out);
}

// Round 3
// 374.772 us; speedup vs baseline: 4.6166x; 1.0063x over previous
//
#include <hip/hip_runtime.h>
#include <math.h>

#define NROWS 65536
#define LLEN  1024
#define RBLOCKS (NROWS / 4)     // 16384 row-kernel blocks (4 rows each)
#define CBLOCKS (NROWS / 256)   // 256 cls-kernel blocks

struct Acc {
    double d2_sum;
    float  gmax;
};

// ---------------- kernel 1: waveform pass (register-resident) ----------------
// One wave per row, 4 waves/block, no LDS staging: lane l holds elements
// {p*256 + 4l .. +3} for p=0..3 (16 floats = 4 float4, perfectly coalesced).
// Neighbors for the second difference come from registers + __shfl.
__global__ __launch_bounds__(256) void row_kernel(const float* __restrict__ wf,
                                                  const float* __restrict__ depth,
                                                  float* __restrict__ eraw,
                                                  float* __restrict__ d2_part,
                                                  float* __restrict__ mx_part) {
    __shared__ float s_d2[4], s_mx[4];
    const int wave = threadIdx.x >> 6;
    const int lane = threadIdx.x & 63;
    const int row  = blockIdx.x * 4 + wave;

    const float4* src = (const float4*)(wf + (size_t)row * LLEN);
    float4 f[4];
#pragma unroll
    for (int p = 0; p < 4; ++p) f[p] = src[p * 64 + lane];

    const float tpos = depth[row] * 10.0f;      // (2*d/4000)*20000

    float d2s = 0.0f, wsum = 0.0f, wesum = 0.0f, mx = -INFINITY;
#pragma unroll
    for (int p = 0; p < 4; ++p) {
        const float x0 = f[p].x, x1 = f[p].y, x2 = f[p].z, x3 = f[p].w;

        float left  = __shfl_up(x3, 1, 64);     // lane l-1's x3
        float right = __shfl_down(x0, 1, 64);   // lane l+1's x0
        // cross-pass stitching (uniform shfl, then per-lane select)
        const float prevTail = __shfl((p > 0) ? f[p - 1].w : x0, 63, 64);
        const float nextHead = __shfl((p < 3) ? f[p + 1].x : x3, 0, 64);
        if (lane == 0)  left  = (p > 0) ? prevTail : x0;   // p==0: b0 -> x1 - x0
        if (lane == 63) right = (p < 3) ? nextHead : x2;   // p==3: bL -> x2 - x3

        const float d2a = x1 - 2.0f * x0 + left;
        const float d2b = x2 - 2.0f * x1 + x0;
        const float d2c = x3 - 2.0f * x2 + x1;
        const float d2d = right - 2.0f * x3 + x2;
        d2s += d2a * d2a + d2b * d2b + d2c * d2c + d2d * d2d;

        mx = fmaxf(fmaxf(mx, fmaxf(x0, x1)), fmaxf(x2, x3));

        const float e0 = (float)(p * 256 + 4 * lane);
#pragma unroll
        for (int j = 0; j < 4; ++j) {
            const float c = (j == 0) ? x0 : (j == 1) ? x1 : (j == 2) ? x2 : x3;
            const float dt = (e0 + (float)j - tpos) * 0.2f;   // sigma = 5
            const float g = __expf(-0.5f * dt * dt);
            wsum  += g;
            wesum += c * c * g;
        }
    }

#pragma unroll
    for (int off = 32; off > 0; off >>= 1) {
        d2s   += __shfl_down(d2s,   off, 64);
        wsum  += __shfl_down(wsum,  off, 64);
        wesum += __shfl_down(wesum, off, 64);
        mx = fmaxf(mx, __shfl_down(mx, off, 64));
    }

    if (lane == 0) {
        eraw[row] = wesum / wsum;
        s_d2[wave] = d2s;
        s_mx[wave] = mx;
    }
    __syncthreads();
    if (threadIdx.x == 0) {
        d2_part[blockIdx.x] = s_d2[0] + s_d2[1] + s_d2[2] + s_d2[3];
        mx_part[blockIdx.x] = fmaxf(fmaxf(s_mx[0], s_mx[1]), fmaxf(s_mx[2], s_mx[3]));
    }
}

// ---------------- kernel 2: fold 16384 partials -> Acc ----------------
__global__ __launch_bounds__(256) void reduce_kernel(const float* __restrict__ d2_part,
                                                     const float* __restrict__ mx_part,
                                                     Acc* __restrict__ acc) {
    __shared__ double s_d2[4];
    __shared__ float  s_mx[4];
    const int wave = threadIdx.x >> 6;
    const int lane = threadIdx.x & 63;

    double d2 = 0.0;
    float mx = -INFINITY;
    for (int i = threadIdx.x; i < RBLOCKS; i += 256) {
        d2 += (double)d2_part[i];
        mx = fmaxf(mx, mx_part[i]);
    }
#pragma unroll
    for (int off = 32; off > 0; off >>= 1) {
        d2 += __shfl_down(d2, off, 64);
        mx = fmaxf(mx, __shfl_down(mx, off, 64));
    }
    if (lane == 0) { s_d2[wave] = d2; s_mx[wave] = mx; }
    __syncthreads();
    if (threadIdx.x == 0) {
        acc->d2_sum = s_d2[0] + s_d2[1] + s_d2[2] + s_d2[3];
        acc->gmax   = fmaxf(fmaxf(s_mx[0], s_mx[1]), fmaxf(s_mx[2], s_mx[3]));
    }
}

// ---------------- kernel 3: CE + argmax + penalty, per-block partials ----------------
__global__ __launch_bounds__(256) void cls_kernel(const float* __restrict__ logits,
                                                  const int* __restrict__ labels,
                                                  const float* __restrict__ eraw,
                                                  const Acc* __restrict__ acc,
                                                  float* __restrict__ nll_part,
                                                  float* __restrict__ pen_part,
                                                  int* __restrict__ nv_part) {
    __shared__ float s_nll[4], s_pen[4];
    __shared__ int   s_nv[4];
    const int wave = threadIdx.x >> 6;
    const int lane = threadIdx.x & 63;
    const int r = blockIdx.x * 256 + threadIdx.x;

    const float4 lg = ((const float4*)logits)[r];
    const float m = fmaxf(fmaxf(lg.x, lg.y), fmaxf(lg.z, lg.w));
    const float lse = m + logf(__expf(lg.x - m) + __expf(lg.y - m) +
                               __expf(lg.z - m) + __expf(lg.w - m));

    const int lab = labels[r];
    const bool valid = (lab != -1);
    const int sl = valid ? lab : 0;
    const float lv = (sl == 0) ? lg.x : (sl == 1) ? lg.y : (sl == 2) ? lg.z : lg.w;
    float nll = valid ? (lse - lv) : 0.0f;

    int pc = 0; float bv = lg.x;
    if (lg.y > bv) { bv = lg.y; pc = 1; }
    if (lg.z > bv) { bv = lg.z; pc = 2; }
    if (lg.w > bv) { bv = lg.w; pc = 3; }

    const float E = eraw[r] / (20.0f * acc->gmax);
    const bool isdef = (pc == 2) || (pc == 3);
    float pen;
    if (isdef) pen = (E < 0.1f) ? (0.1f - E) * (0.1f - E) : 0.0f;
    else       pen = (E > 0.5f) ? (E - 0.5f) * (E - 0.5f) : 0.0f;

    const unsigned long long bal = __ballot(valid);
#pragma unroll
    for (int off = 32; off > 0; off >>= 1) {
        nll += __shfl_down(nll, off, 64);
        pen += __shfl_down(pen, off, 64);
    }
    if (lane == 0) { s_nll[wave] = nll; s_pen[wave] = pen; s_nv[wave] = __popcll(bal); }
    __syncthreads();
    if (threadIdx.x == 0) {
        nll_part[blockIdx.x] = s_nll[0] + s_nll[1] + s_nll[2] + s_nll[3];
        pen_part[blockIdx.x] = s_pen[0] + s_pen[1] + s_pen[2] + s_pen[3];
        nv_part[blockIdx.x]  = s_nv[0] + s_nv[1] + s_nv[2] + s_nv[3];
    }
}

// ---------------- kernel 4: fold 256 cls partials, emit 4 scalars ----------------
__global__ __launch_bounds__(256) void final_kernel(const float* __restrict__ nll_part,
                                                    const float* __restrict__ pen_part,
                                                    const int* __restrict__ nv_part,
                                                    const Acc* __restrict__ acc,
                                                    float* __restrict__ out) {
    __shared__ double s_nll[4], s_pen[4];
    __shared__ int    s_nv[4];
    const int wave = threadIdx.x >> 6;
    const int lane = threadIdx.x & 63;

    double nll = (double)nll_part[threadIdx.x];
    double pen = (double)pen_part[threadIdx.x];
    int nv = nv_part[threadIdx.x];
#pragma unroll
    for (int off = 32; off > 0; off >>= 1) {
        nll += __shfl_down(nll, off, 64);
        pen += __shfl_down(pen, off, 64);
        nv  += __shfl_down(nv,  off, 64);
    }
    if (lane == 0) { s_nll[wave] = nll; s_pen[wave] = pen; s_nv[wave] = nv; }
    __syncthreads();
    if (threadIdx.x == 0) {
        const double nll_s = s_nll[0] + s_nll[1] + s_nll[2] + s_nll[3];
        const double pen_s = s_pen[0] + s_pen[1] + s_pen[2] + s_pen[3];
        const int    nv_s  = s_nv[0] + s_nv[1] + s_nv[2] + s_nv[3];
        const double cls  = (nv_s > 0) ? nll_s / (double)nv_s : 0.0;
        const double wave_l = acc->d2_sum * (9900.0 * 9900.0) / ((double)NROWS * (double)LLEN);
        const double phys = pen_s / (double)NROWS;
        out[0] = (float)(cls + 0.1 * wave_l + 0.1 * phys);
        out[1] = (float)cls;
        out[2] = (float)wave_l;
        out[3] = (float)phys;
    }
}

extern "C" void kernel_launch(void* const* d_in, const int* in_sizes, int n_in,
                              void* d_out, int out_size, void* d_ws, size_t ws_size,
                              hipStream_t stream) {
    const float* wf     = (const float*)d_in[0];
    const float* logits = (const float*)d_in[1];
    const float* depth  = (const float*)d_in[2];
    const int*   labels = (const int*)d_in[3];
    float* out = (float*)d_out;

    char* ws = (char*)d_ws;
    Acc*   acc      = (Acc*)ws;                       ws += 256;
    float* eraw     = (float*)ws;                     ws += NROWS * sizeof(float);
    float* d2_part  = (float*)ws;                     ws += RBLOCKS * sizeof(float);
    float* mx_part  = (float*)ws;                     ws += RBLOCKS * sizeof(float);
    float* nll_part = (float*)ws;                     ws += CBLOCKS * sizeof(float);
    float* pen_part = (float*)ws;                     ws += CBLOCKS * sizeof(float);
    int*   nv_part  = (int*)ws;

    row_kernel<<<RBLOCKS, 256, 0, stream>>>(wf, depth, eraw, d2_part, mx_part);
    reduce_kernel<<<1, 256, 0, stream>>>(d2_part, mx_part, acc);
    cls_kernel<<<CBLOCKS, 256, 0, stream>>>(logits, labels, eraw, acc, nll_part, pen_part, nv_part);
    final_kernel<<<1, 256, 0, stream>>>(nll_part, pen_part, nv_part, acc, out);
}

// Round 4
// 371.994 us; speedup vs baseline: 4.6511x; 1.0075x over previous
//
#include <hip/hip_runtime.h>
#include <math.h>

#define NROWS 65536
#define LLEN  1024
#define RBLOCKS (NROWS / 8)     // 8192 blocks: 4 waves/block x 2 rows/wave
#define CBLOCKS (NROWS / 256)   // 256 cls-kernel blocks

struct Acc {
    double d2_sum;
    float  gmax;
};

// Per-row compute on register-resident data. f[p] holds elements
// {p*256 + 4*lane .. +3}. Gaussian window evaluated only for passes within
// +-75 samples of tpos: outside that, expf underflows to exactly 0.0f, so
// skipping is bit-exact.
__device__ __forceinline__ void row_compute(const float4* f, int lane, float tpos,
                                            float& d2s, float& mx,
                                            float& wsum, float& wesum) {
    d2s = 0.0f; mx = -INFINITY; wsum = 0.0f; wesum = 0.0f;
#pragma unroll
    for (int p = 0; p < 4; ++p) {
        const float x0 = f[p].x, x1 = f[p].y, x2 = f[p].z, x3 = f[p].w;

        float left  = __shfl_up(x3, 1, 64);
        float right = __shfl_down(x0, 1, 64);
        const float prevTail = __shfl((p > 0) ? f[p - 1].w : x0, 63, 64);
        const float nextHead = __shfl((p < 3) ? f[p + 1].x : x3, 0, 64);
        if (lane == 0)  left  = (p > 0) ? prevTail : x0;   // p==0: w1 - w0
        if (lane == 63) right = (p < 3) ? nextHead : x2;   // p==3: w[-2] - w[-1]

        const float d2a = x1 - 2.0f * x0 + left;
        const float d2b = x2 - 2.0f * x1 + x0;
        const float d2c = x3 - 2.0f * x2 + x1;
        const float d2d = right - 2.0f * x3 + x2;
        d2s += d2a * d2a + d2b * d2b + d2c * d2c + d2d * d2d;

        mx = fmaxf(fmaxf(mx, fmaxf(x0, x1)), fmaxf(x2, x3));

        // wave-uniform window skip (tpos is uniform across the wave)
        const float pstart = (float)(p * 256);
        if (tpos > pstart - 75.0f && tpos < pstart + 330.0f) {
            const float e0 = pstart + (float)(4 * lane);
#pragma unroll
            for (int j = 0; j < 4; ++j) {
                const float c = (j == 0) ? x0 : (j == 1) ? x1 : (j == 2) ? x2 : x3;
                const float dt = (e0 + (float)j - tpos) * 0.2f;   // sigma = 5
                const float g = __expf(-0.5f * dt * dt);
                wsum  += g;
                wesum += c * c * g;
            }
        }
    }
}

// ---------------- kernel 1: waveform pass ----------------
// 4 waves/block, 2 consecutive rows per wave, all loads issued up front.
__global__ __launch_bounds__(256) void row_kernel(const float* __restrict__ wf,
                                                  const float* __restrict__ depth,
                                                  float* __restrict__ eraw,
                                                  float* __restrict__ d2_part,
                                                  float* __restrict__ mx_part) {
    __shared__ float s_d2[4], s_mx[4];
    const int wave = threadIdx.x >> 6;
    const int lane = threadIdx.x & 63;
    const int r0 = (blockIdx.x * 4 + wave) * 2;

    const float4* srcA = (const float4*)(wf + (size_t)r0 * LLEN);
    const float4* srcB = srcA + (LLEN / 4);
    float4 fA[4], fB[4];
#pragma unroll
    for (int p = 0; p < 4; ++p) fA[p] = srcA[p * 64 + lane];
#pragma unroll
    for (int p = 0; p < 4; ++p) fB[p] = srcB[p * 64 + lane];
    const float2 dep = *(const float2*)(depth + r0);   // r0 even -> 8B aligned

    float d2sA, mxA, wsA, weA, d2sB, mxB, wsB, weB;
    row_compute(fA, lane, dep.x * 10.0f, d2sA, mxA, wsA, weA);
    row_compute(fB, lane, dep.y * 10.0f, d2sB, mxB, wsB, weB);

    // per-row window reduce (2 values each)
#pragma unroll
    for (int off = 32; off > 0; off >>= 1) {
        wsA += __shfl_down(wsA, off, 64);
        weA += __shfl_down(weA, off, 64);
        wsB += __shfl_down(wsB, off, 64);
        weB += __shfl_down(weB, off, 64);
    }
    // combined d2/max reduce across the row pair
    float d2s = d2sA + d2sB;
    float mx  = fmaxf(mxA, mxB);
#pragma unroll
    for (int off = 32; off > 0; off >>= 1) {
        d2s += __shfl_down(d2s, off, 64);
        mx = fmaxf(mx, __shfl_down(mx, off, 64));
    }

    if (lane == 0) {
        eraw[r0]     = weA / wsA;
        eraw[r0 + 1] = weB / wsB;
        s_d2[wave] = d2s;
        s_mx[wave] = mx;
    }
    __syncthreads();
    if (threadIdx.x == 0) {
        d2_part[blockIdx.x] = s_d2[0] + s_d2[1] + s_d2[2] + s_d2[3];
        mx_part[blockIdx.x] = fmaxf(fmaxf(s_mx[0], s_mx[1]), fmaxf(s_mx[2], s_mx[3]));
    }
}

// ---------------- kernel 2: fold 8192 partials -> Acc ----------------
__global__ __launch_bounds__(256) void reduce_kernel(const float* __restrict__ d2_part,
                                                     const float* __restrict__ mx_part,
                                                     Acc* __restrict__ acc) {
    __shared__ double s_d2[4];
    __shared__ float  s_mx[4];
    const int wave = threadIdx.x >> 6;
    const int lane = threadIdx.x & 63;

    double d2 = 0.0;
    float mx = -INFINITY;
    for (int i = threadIdx.x; i < RBLOCKS; i += 256) {
        d2 += (double)d2_part[i];
        mx = fmaxf(mx, mx_part[i]);
    }
#pragma unroll
    for (int off = 32; off > 0; off >>= 1) {
        d2 += __shfl_down(d2, off, 64);
        mx = fmaxf(mx, __shfl_down(mx, off, 64));
    }
    if (lane == 0) { s_d2[wave] = d2; s_mx[wave] = mx; }
    __syncthreads();
    if (threadIdx.x == 0) {
        acc->d2_sum = s_d2[0] + s_d2[1] + s_d2[2] + s_d2[3];
        acc->gmax   = fmaxf(fmaxf(s_mx[0], s_mx[1]), fmaxf(s_mx[2], s_mx[3]));
    }
}

// ---------------- kernel 3: CE + argmax + penalty ----------------
__global__ __launch_bounds__(256) void cls_kernel(const float* __restrict__ logits,
                                                  const int* __restrict__ labels,
                                                  const float* __restrict__ eraw,
                                                  const Acc* __restrict__ acc,
                                                  float* __restrict__ nll_part,
                                                  float* __restrict__ pen_part,
                                                  int* __restrict__ nv_part) {
    __shared__ float s_nll[4], s_pen[4];
    __shared__ int   s_nv[4];
    const int wave = threadIdx.x >> 6;
    const int lane = threadIdx.x & 63;
    const int r = blockIdx.x * 256 + threadIdx.x;

    const float4 lg = ((const float4*)logits)[r];
    const float m = fmaxf(fmaxf(lg.x, lg.y), fmaxf(lg.z, lg.w));
    const float lse = m + logf(__expf(lg.x - m) + __expf(lg.y - m) +
                               __expf(lg.z - m) + __expf(lg.w - m));

    const int lab = labels[r];
    const bool valid = (lab != -1);
    const int sl = valid ? lab : 0;
    const float lv = (sl == 0) ? lg.x : (sl == 1) ? lg.y : (sl == 2) ? lg.z : lg.w;
    float nll = valid ? (lse - lv) : 0.0f;

    int pc = 0; float bv = lg.x;
    if (lg.y > bv) { bv = lg.y; pc = 1; }
    if (lg.z > bv) { bv = lg.z; pc = 2; }
    if (lg.w > bv) { bv = lg.w; pc = 3; }

    const float E = eraw[r] / (20.0f * acc->gmax);
    const bool isdef = (pc == 2) || (pc == 3);
    float pen;
    if (isdef) pen = (E < 0.1f) ? (0.1f - E) * (0.1f - E) : 0.0f;
    else       pen = (E > 0.5f) ? (E - 0.5f) * (E - 0.5f) : 0.0f;

    const unsigned long long bal = __ballot(valid);
#pragma unroll
    for (int off = 32; off > 0; off >>= 1) {
        nll += __shfl_down(nll, off, 64);
        pen += __shfl_down(pen, off, 64);
    }
    if (lane == 0) { s_nll[wave] = nll; s_pen[wave] = pen; s_nv[wave] = __popcll(bal); }
    __syncthreads();
    if (threadIdx.x == 0) {
        nll_part[blockIdx.x] = s_nll[0] + s_nll[1] + s_nll[2] + s_nll[3];
        pen_part[blockIdx.x] = s_pen[0] + s_pen[1] + s_pen[2] + s_pen[3];
        nv_part[blockIdx.x]  = s_nv[0] + s_nv[1] + s_nv[2] + s_nv[3];
    }
}

// ---------------- kernel 4: fold 256 cls partials, emit 4 scalars ----------------
__global__ __launch_bounds__(256) void final_kernel(const float* __restrict__ nll_part,
                                                    const float* __restrict__ pen_part,
                                                    const int* __restrict__ nv_part,
                                                    const Acc* __restrict__ acc,
                                                    float* __restrict__ out) {
    __shared__ double s_nll[4], s_pen[4];
    __shared__ int    s_nv[4];
    const int wave = threadIdx.x >> 6;
    const int lane = threadIdx.x & 63;

    double nll = (double)nll_part[threadIdx.x];
    double pen = (double)pen_part[threadIdx.x];
    int nv = nv_part[threadIdx.x];
#pragma unroll
    for (int off = 32; off > 0; off >>= 1) {
        nll += __shfl_down(nll, off, 64);
        pen += __shfl_down(pen, off, 64);
        nv  += __shfl_down(nv,  off, 64);
    }
    if (lane == 0) { s_nll[wave] = nll; s_pen[wave] = pen; s_nv[wave] = nv; }
    __syncthreads();
    if (threadIdx.x == 0) {
        const double nll_s = s_nll[0] + s_nll[1] + s_nll[2] + s_nll[3];
        const double pen_s = s_pen[0] + s_pen[1] + s_pen[2] + s_pen[3];
        const int    nv_s  = s_nv[0] + s_nv[1] + s_nv[2] + s_nv[3];
        const double cls  = (nv_s > 0) ? nll_s / (double)nv_s : 0.0;
        const double wave_l = acc->d2_sum * (9900.0 * 9900.0) / ((double)NROWS * (double)LLEN);
        const double phys = pen_s / (double)NROWS;
        out[0] = (float)(cls + 0.1 * wave_l + 0.1 * phys);
        out[1] = (float)cls;
        out[2] = (float)wave_l;
        out[3] = (float)phys;
    }
}

extern "C" void kernel_launch(void* const* d_in, const int* in_sizes, int n_in,
                              void* d_out, int out_size, void* d_ws, size_t ws_size,
                              hipStream_t stream) {
    const float* wf     = (const float*)d_in[0];
    const float* logits = (const float*)d_in[1];
    const float* depth  = (const float*)d_in[2];
    const int*   labels = (const int*)d_in[3];
    float* out = (float*)d_out;

    char* ws = (char*)d_ws;
    Acc*   acc      = (Acc*)ws;                       ws += 256;
    float* eraw     = (float*)ws;                     ws += NROWS * sizeof(float);
    float* d2_part  = (float*)ws;                     ws += RBLOCKS * sizeof(float);
    float* mx_part  = (float*)ws;                     ws += RBLOCKS * sizeof(float);
    float* nll_part = (float*)ws;                     ws += CBLOCKS * sizeof(float);
    float* pen_part = (float*)ws;                     ws += CBLOCKS * sizeof(float);
    int*   nv_part  = (int*)ws;

    row_kernel<<<RBLOCKS, 256, 0, stream>>>(wf, depth, eraw, d2_part, mx_part);
    reduce_kernel<<<1, 256, 0, stream>>>(d2_part, mx_part, acc);
    cls_kernel<<<CBLOCKS, 256, 0, stream>>>(logits, labels, eraw, acc, nll_part, pen_part, nv_part);
    final_kernel<<<1, 256, 0, stream>>>(nll_part, pen_part, nv_part, acc, out);
}